// Round 2
// baseline (5632.017 us; speedup 1.0000x reference)
//
#include <hip/hip_runtime.h>

// ODEFunc CNF dynamics: per row r (B=1e6):
//   h1 = elu(W1 z + b1); [h2,u2,v2] = W2 [h1,u,v]; out = W3 elu(h2)+b3,
//   trace = W3[0,:]·(elu'(h2)*u2) + W3[1,:]·(elu'(h2)*v2); out[:,2] = -trace
//
// R2 design: one thread per row. ALL weight reads use wave-uniform global
// addresses -> compiler emits s_load (SMEM pipe, scalar cache), and each
// v_fma_f32 consumes the weight as its single SGPR operand. No LDS at all.
// No launch_bounds cap: h1/uu/vv (192 floats) stay in real VGPRs (~232),
// ~8 waves/CU, no AGPR spill traffic. VALU floor ~165 us (24.6 GFLOP @157TF).

__global__ void odefunc_kernel(const float* __restrict__ zin,
                               const float* __restrict__ W1, const float* __restrict__ b1,
                               const float* __restrict__ W2, const float* __restrict__ b2,
                               const float* __restrict__ W3, const float* __restrict__ b3,
                               float* __restrict__ out, int B)
{
    int r = blockIdx.x * blockDim.x + threadIdx.x;
    if (r >= B) return;

    float z0 = zin[3 * r + 0];
    float z1 = zin[3 * r + 1];

    // ---- Layer 1 + ELU + tangent seeds (registers; weights via SMEM) ----
    float h1[64], uu[64], vv[64];
#pragma unroll
    for (int j = 0; j < 64; ++j) {
        float w0 = W1[2 * j + 0];       // uniform -> s_load
        float w1 = W1[2 * j + 1];
        float a = fmaf(w0, z0, fmaf(w1, z1, b1[j]));
        float ex = __expf(fminf(a, 0.f));   // clamp: avoid inf for a>0
        bool pos = a > 0.f;
        float h = pos ? a : (ex - 1.f);     // elu
        float g = pos ? 1.f : ex;           // elu'
        h1[j] = h;
        uu[j] = g * w0;                     // d(h1_j)/dz0
        vv[j] = g * w1;                     // d(h1_j)/dz1
    }

    // ---- Layer 2 (3 matvecs vs W2) + ELU + layer 3 folded ----
    float out0 = b3[0], out1 = b3[1], tr = 0.f;
#pragma unroll 2
    for (int k = 0; k < 64; ++k) {
        const float4* wrow = (const float4*)(W2 + k * 64);  // uniform
        float acc = b2[k];
        float d0 = 0.f, d1 = 0.f;
#pragma unroll
        for (int j4 = 0; j4 < 16; ++j4) {
            float4 w = wrow[j4];            // uniform -> s_load_dwordx4
            int j = 4 * j4;
            acc = fmaf(w.x, h1[j + 0], acc);
            d0  = fmaf(w.x, uu[j + 0], d0);
            d1  = fmaf(w.x, vv[j + 0], d1);
            acc = fmaf(w.y, h1[j + 1], acc);
            d0  = fmaf(w.y, uu[j + 1], d0);
            d1  = fmaf(w.y, vv[j + 1], d1);
            acc = fmaf(w.z, h1[j + 2], acc);
            d0  = fmaf(w.z, uu[j + 2], d0);
            d1  = fmaf(w.z, vv[j + 2], d1);
            acc = fmaf(w.w, h1[j + 3], acc);
            d0  = fmaf(w.w, uu[j + 3], d0);
            d1  = fmaf(w.w, vv[j + 3], d1);
        }
        float ex = __expf(fminf(acc, 0.f));
        bool pos = acc > 0.f;
        float h = pos ? acc : (ex - 1.f);
        float g = pos ? 1.f : ex;
        float w30 = W3[k];                  // W3[0,k], uniform
        float w31 = W3[64 + k];             // W3[1,k]
        out0 = fmaf(w30, h, out0);
        out1 = fmaf(w31, h, out1);
        tr = fmaf(w30, g * d0, fmaf(w31, g * d1, tr));
    }

    out[3 * r + 0] = out0;
    out[3 * r + 1] = out1;
    out[3 * r + 2] = -tr;
}

extern "C" void kernel_launch(void* const* d_in, const int* in_sizes, int n_in,
                              void* d_out, int out_size, void* d_ws, size_t ws_size,
                              hipStream_t stream) {
    // d_in: 0=t(unused) 1=z_and_logp 2=W1 3=b1 4=W2 5=b2 6=W3 7=b3
    const float* zin = (const float*)d_in[1];
    const float* W1  = (const float*)d_in[2];
    const float* b1  = (const float*)d_in[3];
    const float* W2  = (const float*)d_in[4];
    const float* b2  = (const float*)d_in[5];
    const float* W3  = (const float*)d_in[6];
    const float* b3  = (const float*)d_in[7];
    float* out = (float*)d_out;

    int B = in_sizes[1] / 3;
    int grid = (B + 255) / 256;
    odefunc_kernel<<<grid, 256, 0, stream>>>(zin, W1, b1, W2, b2, W3, b3, out, B);
}

// Round 3
// 468.530 us; speedup vs baseline: 12.0206x; 12.0206x over previous
//
#include <hip/hip_runtime.h>

// ODEFunc CNF dynamics: per row r (B=1e6):
//   h1 = elu(W1 z + b1); [h2,u2,v2] = W2 [h1,u,v]; out = W3 elu(h2)+b3,
//   trace = W3[0,:]*(elu'(h2)*u2) + W3[1,:]*(elu'(h2)*v2); out[:,2] = -trace
//
// R3: one thread per row. Weight reads use wave-uniform global addresses ->
// scalar s_load (SMEM pipe, scalar cache); v_fma_f32 consumes the weight as
// its single SGPR operand. No LDS.
// __launch_bounds__(256, 1): 512-VGPR budget so h1/uu/vv (192 floats) stay in
// REAL VGPRs. R1 (cap 128) -> AGPR shuffle, 349us. R2 (no bounds, cap 64) ->
// scratch spill, 5632us (WRITE_SIZE showed exactly 192*4B*1M = 768MB).
// VALU floor ~160us (24.6 GFLOP @ 157 TF fp32 vector).

__global__ __launch_bounds__(256, 1)
void odefunc_kernel(const float* __restrict__ zin,
                    const float* __restrict__ W1, const float* __restrict__ b1,
                    const float* __restrict__ W2, const float* __restrict__ b2,
                    const float* __restrict__ W3, const float* __restrict__ b3,
                    float* __restrict__ out, int B)
{
    int r = blockIdx.x * blockDim.x + threadIdx.x;
    if (r >= B) return;

    float z0 = zin[3 * r + 0];
    float z1 = zin[3 * r + 1];

    // ---- Layer 1 + ELU + tangent seeds (registers; weights via SMEM) ----
    float h1[64], uu[64], vv[64];
#pragma unroll
    for (int j = 0; j < 64; ++j) {
        float w0 = W1[2 * j + 0];       // uniform address -> s_load
        float w1 = W1[2 * j + 1];
        float a = fmaf(w0, z0, fmaf(w1, z1, b1[j]));
        float ex = __expf(fminf(a, 0.f));   // clamp: avoid inf for a>0
        bool pos = a > 0.f;
        float h = pos ? a : (ex - 1.f);     // elu
        float g = pos ? 1.f : ex;           // elu'
        h1[j] = h;
        uu[j] = g * w0;                     // d(h1_j)/dz0
        vv[j] = g * w1;                     // d(h1_j)/dz1
    }

    // ---- Layer 2 (3 matvecs vs W2) + ELU + layer 3 folded ----
    float out0 = b3[0], out1 = b3[1], tr = 0.f;
#pragma unroll 2
    for (int k = 0; k < 64; ++k) {
        const float4* wrow = (const float4*)(W2 + k * 64);  // uniform
        float acc = b2[k];
        float d0 = 0.f, d1 = 0.f;
#pragma unroll
        for (int j4 = 0; j4 < 16; ++j4) {
            float4 w = wrow[j4];            // uniform -> s_load_dwordx4
            int j = 4 * j4;
            acc = fmaf(w.x, h1[j + 0], acc);
            d0  = fmaf(w.x, uu[j + 0], d0);
            d1  = fmaf(w.x, vv[j + 0], d1);
            acc = fmaf(w.y, h1[j + 1], acc);
            d0  = fmaf(w.y, uu[j + 1], d0);
            d1  = fmaf(w.y, vv[j + 1], d1);
            acc = fmaf(w.z, h1[j + 2], acc);
            d0  = fmaf(w.z, uu[j + 2], d0);
            d1  = fmaf(w.z, vv[j + 2], d1);
            acc = fmaf(w.w, h1[j + 3], acc);
            d0  = fmaf(w.w, uu[j + 3], d0);
            d1  = fmaf(w.w, vv[j + 3], d1);
        }
        float ex = __expf(fminf(acc, 0.f));
        bool pos = acc > 0.f;
        float h = pos ? acc : (ex - 1.f);
        float g = pos ? 1.f : ex;
        float w30 = W3[k];                  // W3[0,k], uniform
        float w31 = W3[64 + k];             // W3[1,k]
        out0 = fmaf(w30, h, out0);
        out1 = fmaf(w31, h, out1);
        tr = fmaf(w30, g * d0, fmaf(w31, g * d1, tr));
    }

    out[3 * r + 0] = out0;
    out[3 * r + 1] = out1;
    out[3 * r + 2] = -tr;
}

extern "C" void kernel_launch(void* const* d_in, const int* in_sizes, int n_in,
                              void* d_out, int out_size, void* d_ws, size_t ws_size,
                              hipStream_t stream) {
    // d_in: 0=t(unused) 1=z_and_logp 2=W1 3=b1 4=W2 5=b2 6=W3 7=b3
    const float* zin = (const float*)d_in[1];
    const float* W1  = (const float*)d_in[2];
    const float* b1  = (const float*)d_in[3];
    const float* W2  = (const float*)d_in[4];
    const float* b2  = (const float*)d_in[5];
    const float* W3  = (const float*)d_in[6];
    const float* b3  = (const float*)d_in[7];
    float* out = (float*)d_out;

    int B = in_sizes[1] / 3;
    int grid = (B + 255) / 256;
    odefunc_kernel<<<grid, 256, 0, stream>>>(zin, W1, b1, W2, b2, W3, b3, out, B);
}